// Round 16
// baseline (115.709 us; speedup 1.0000x reference)
//
#include <hip/hip_runtime.h>
#include <stdint.h>
#include <stddef.h>

typedef __bf16 bf16;
typedef bf16 bf16x2 __attribute__((ext_vector_type(2)));
typedef bf16 bf16x4 __attribute__((ext_vector_type(4)));
typedef bf16 bf16x8 __attribute__((ext_vector_type(8)));
typedef float f32x4 __attribute__((ext_vector_type(4)));
typedef float f32x16 __attribute__((ext_vector_type(16)));

#define MFMA16(a, b, c) __builtin_amdgcn_mfma_f32_16x16x32_bf16((a), (b), (c), 0, 0, 0)
#define MFMA32(a, b, c) __builtin_amdgcn_mfma_f32_32x32x16_bf16((a), (b), (c), 0, 0, 0)

// async global->LDS, 16B per lane, dest = wave-uniform base + lane*16
#define GLD_LDS16(g, l)                                          \
    __builtin_amdgcn_global_load_lds(                            \
        (const __attribute__((address_space(1))) void*)(g),      \
        (__attribute__((address_space(3))) void*)(l), 16, 0, 0)

// ---------------- fused (weights cast | pos-add + LayerNorm + cast) ----------------
__global__ __launch_bounds__(256) void prep_all(const float* __restrict__ wq,
                                                const float* __restrict__ wk,
                                                const float* __restrict__ wv,
                                                const float* __restrict__ wp,
                                                bf16* __restrict__ wout,
                                                const float* __restrict__ q,
                                                const float* __restrict__ k,
                                                const float* __restrict__ v,
                                                const float* __restrict__ qpos,
                                                const float* __restrict__ kpos,
                                                const float* __restrict__ lnqw,
                                                const float* __restrict__ lnqb,
                                                const float* __restrict__ lnkw,
                                                const float* __restrict__ lnkb,
                                                const float* __restrict__ lnvw,
                                                const float* __restrict__ lnvb,
                                                bf16* __restrict__ out) {
    int bx = blockIdx.x;
    int t = threadIdx.x;
    if (bx < 4096) {
        int i = (bx * 256 + t) * 4;
        const float* src;
        int j = i;
        if (i < (1 << 20)) { src = wq; }
        else if (i < (2 << 20)) { src = wk; j = i - (1 << 20); }
        else if (i < (3 << 20)) { src = wv; j = i - (2 << 20); }
        else { src = wp; j = i - (3 << 20); }
        float4 vv = *(const float4*)(src + j);
        bf16x4 o;
        o[0] = (bf16)vv.x; o[1] = (bf16)vv.y; o[2] = (bf16)vv.z; o[3] = (bf16)vv.w;
        *(bf16x4*)(wout + i) = o;
        return;
    }
    int row = bx - 4096;
    const float *x, *pos, *w, *bb;
    int r = row;
    if (row < 2048)      { x = q; pos = qpos; w = lnqw; bb = lnqb; }
    else if (row < 6144) { r = row - 2048; x = k; pos = kpos; w = lnkw; bb = lnkb; }
    else                 { r = row - 6144; x = v; pos = nullptr; w = lnvw; bb = lnvb; }

    float4 vv = ((const float4*)(x + (size_t)r * 1024))[t];
    if (pos != nullptr) {
        float4 p = ((const float4*)(pos + (size_t)r * 1024))[t];
        vv.x += p.x; vv.y += p.y; vv.z += p.z; vv.w += p.w;
    }
    float s1 = vv.x + vv.y + vv.z + vv.w;
    float s2 = vv.x * vv.x + vv.y * vv.y + vv.z * vv.z + vv.w * vv.w;
#pragma unroll
    for (int off = 1; off < 64; off <<= 1) {
        s1 += __shfl_xor(s1, off);
        s2 += __shfl_xor(s2, off);
    }
    __shared__ float red[8];
    int wave = t >> 6;
    if ((t & 63) == 0) { red[wave * 2] = s1; red[wave * 2 + 1] = s2; }
    __syncthreads();
    s1 = red[0] + red[2] + red[4] + red[6];
    s2 = red[1] + red[3] + red[5] + red[7];
    float mu = s1 * (1.0f / 1024.0f);
    float var = s2 * (1.0f / 1024.0f) - mu * mu;
    float rstd = rsqrtf(var + 1e-5f);
    float4 wv4 = ((const float4*)w)[t];
    float4 bv4 = ((const float4*)bb)[t];
    bf16x4 o;
    o[0] = (bf16)((vv.x - mu) * rstd * wv4.x + bv4.x);
    o[1] = (bf16)((vv.y - mu) * rstd * wv4.y + bv4.y);
    o[2] = (bf16)((vv.z - mu) * rstd * wv4.z + bv4.z);
    o[3] = (bf16)((vv.w - mu) * rstd * wv4.w + bv4.w);
    *(bf16x4*)(out + (size_t)row * 1024 + t * 4) = o;
}

// ---------------- gemm1 (QKV): BM=128, BK=64, swizzled staging, counted vmcnt -------------
// out[10240,1024] = xn @ W^T (W per row-range: wq/wk/wv). v-rows (>=6144) -> Vt transposed.
// Per K-step (64): barrier -> stage next (8 ld/thread, XOR chunk swizzle) -> vmcnt(8)
// -> barrier -> 2 halves x 16 MFMA. Swizzle cancels on read (attn-proven T21 pattern);
// fragment banks ~2-way (free) vs BK=32's ~8-way.
__global__ __launch_bounds__(256) void gemm_qkv(const bf16* __restrict__ A,
                                                const bf16* __restrict__ w0,
                                                const bf16* __restrict__ w1,
                                                const bf16* __restrict__ w2,
                                                bf16* __restrict__ out,
                                                bf16* __restrict__ vt) {
    __shared__ bf16 As[2][128 * 64];
    __shared__ bf16 Bs[2][128 * 64];
    int bxr = blockIdx.x;
    int bx = (bxr & 7) * 80 + (bxr >> 3);   // XCD swizzle (640 blocks)
    int tileN = bx & 7;
    int tileM = bx >> 3;
    int t = threadIdx.x;
    int wave = t >> 6, lane = t & 63;
    int lr = lane & 15, lg = lane >> 4;
    int wr = wave >> 1, wc = wave & 1;
    int lr7 = lr & 7;
    int rowBase = tileM * 128;
    const bf16* W = (rowBase < 2048) ? w0 : ((rowBase < 6144) ? w1 : w2);
    const bf16* Ab = A + (size_t)rowBase * 1024;
    const bf16* Wb = W + (size_t)(tileN * 128) * 1024;

    // staging: chunk o in 0..1023 (128 rows x 8 chunks of 16B); swz col cc=(o&7)^(row&7)
#define QSTAGE(bufi, k0n)                                                     \
    {                                                                         \
        _Pragma("unroll")                                                     \
        for (int i = 0; i < 4; ++i) {                                         \
            int o = t + 256 * i;                                              \
            int row = o >> 3;                                                 \
            int cc = (o & 7) ^ (row & 7);                                     \
            GLD_LDS16(Ab + (size_t)row * 1024 + (k0n) + cc * 8,               \
                      (char*)As[bufi] + o * 16);                              \
            GLD_LDS16(Wb + (size_t)row * 1024 + (k0n) + cc * 8,               \
                      (char*)Bs[bufi] + o * 16);                              \
        }                                                                     \
    }

    const f32x4 zero4 = {0.f, 0.f, 0.f, 0.f};
    f32x4 acc[4][4];
#pragma unroll
    for (int i = 0; i < 4; ++i)
#pragma unroll
        for (int j = 0; j < 4; ++j) acc[i][j] = zero4;

    QSTAGE(0, 0);
    __syncthreads();   // prologue drain
    int gbuf = 0;
    for (int k0 = 0; k0 < 1024; k0 += 64) {
        __builtin_amdgcn_s_barrier();   // all waves done reading gbuf^1 (prev iter)
        if (k0 + 64 < 1024) {
            QSTAGE(gbuf ^ 1, k0 + 64);
            asm volatile("s_waitcnt vmcnt(8)" ::: "memory");
        } else {
            asm volatile("s_waitcnt vmcnt(0)" ::: "memory");
        }
        __builtin_amdgcn_s_barrier();   // current-tile loads landed everywhere
#pragma unroll
        for (int h = 0; h < 2; ++h) {
            bf16x8 af[4], bfr[4];
#pragma unroll
            for (int mf = 0; mf < 4; ++mf)
                af[mf] = *(const bf16x8*)((const char*)As[gbuf] +
                                          (wr * 64 + mf * 16 + lr) * 128 +
                                          (((h * 4 + lg) ^ lr7) << 4));
#pragma unroll
            for (int nf = 0; nf < 4; ++nf)
                bfr[nf] = *(const bf16x8*)((const char*)Bs[gbuf] +
                                           (wc * 64 + nf * 16 + lr) * 128 +
                                           (((h * 4 + lg) ^ lr7) << 4));
            __builtin_amdgcn_s_setprio(1);
#pragma unroll
            for (int mf = 0; mf < 4; ++mf)
#pragma unroll
                for (int nf = 0; nf < 4; ++nf)
                    acc[mf][nf] = MFMA16(af[mf], bfr[nf], acc[mf][nf]);
            __builtin_amdgcn_s_setprio(0);
        }
        gbuf ^= 1;
    }
#undef QSTAGE
    bool isV = (rowBase >= 6144);
    if (!isV) {
#pragma unroll
        for (int nf = 0; nf < 4; ++nf) {
            int ncol = tileN * 128 + wc * 64 + nf * 16 + lr;
#pragma unroll
            for (int mf = 0; mf < 4; ++mf) {
                int mrow = rowBase + wr * 64 + mf * 16 + lg * 4;
#pragma unroll
                for (int r = 0; r < 4; ++r)
                    out[(size_t)(mrow + r) * 1024 + ncol] = (bf16)acc[mf][nf][r];
            }
        }
    } else {
        int b2 = (rowBase - 6144) >> 11;
        int kb = rowBase - 6144 - (b2 << 11);
#pragma unroll
        for (int nf = 0; nf < 4; ++nf) {
            int ncol = tileN * 128 + wc * 64 + nf * 16 + lr;
            int h2 = ncol >> 6, d2 = ncol & 63;
            bf16* vrow = vt + ((size_t)((b2 * 16 + h2) * 64 + d2)) * 2048;
#pragma unroll
            for (int mf = 0; mf < 4; ++mf) {
                int kk = kb + wr * 64 + mf * 16 + lg * 4;
                bf16x4 pv;
#pragma unroll
                for (int r = 0; r < 4; ++r) pv[r] = (bf16)acc[mf][nf][r];
                *(bf16x4*)(vrow + kk) = pv;
            }
        }
    }
}

// ---------------- gemm2 (proj): BM=64, BK=32, counted-vmcnt (round-13 proven) -------------
__global__ __launch_bounds__(256) void gemm_proj(const bf16* __restrict__ A,
                                                 const bf16* __restrict__ w0,
                                                 const float* __restrict__ bias,
                                                 float* __restrict__ out) {
    __shared__ bf16 As[2][64 * 32];
    __shared__ bf16 Bs[2][128 * 32];
    int bxr = blockIdx.x;
    int bx = (bxr & 7) * 32 + (bxr >> 3);   // XCD swizzle (256 blocks)
    int tileN = bx & 7;
    int tileM = bx >> 3;
    int t = threadIdx.x;
    int wave = t >> 6, lane = t & 63;
    int lr = lane & 15, lg = lane >> 4;
    int wc = wave;
    int rowBase = tileM * 64;
    const bf16* Ab = A + (size_t)rowBase * 1024;
    const bf16* Wb = w0 + (size_t)(tileN * 128) * 1024;

    int o16b0 = wave * 128 + lane;
    int o16b1 = o16b0 + 64;

#define PSTAGE(bufi, k0n)                                                     \
    {                                                                         \
        GLD_LDS16(Ab + (size_t)(t >> 2) * 1024 + (k0n) + (t & 3) * 8,         \
                  (char*)As[bufi] + t * 16);                                  \
        GLD_LDS16(Wb + (size_t)(o16b0 >> 2) * 1024 + (k0n) + (o16b0 & 3) * 8, \
                  (char*)Bs[bufi] + o16b0 * 16);                              \
        GLD_LDS16(Wb + (size_t)(o16b1 >> 2) * 1024 + (k0n) + (o16b1 & 3) * 8, \
                  (char*)Bs[bufi] + o16b1 * 16);                              \
    }

    const f32x4 zero4 = {0.f, 0.f, 0.f, 0.f};
    f32x4 acc[4][2];
#pragma unroll
    for (int i = 0; i < 4; ++i) { acc[i][0] = zero4; acc[i][1] = zero4; }

    PSTAGE(0, 0);
    __syncthreads();
    int gbuf = 0;
    for (int k0 = 0; k0 < 1024; k0 += 32) {
        __builtin_amdgcn_s_barrier();
        if (k0 + 32 < 1024) {
            PSTAGE(gbuf ^ 1, k0 + 32);
            asm volatile("s_waitcnt vmcnt(3)" ::: "memory");
        } else {
            asm volatile("s_waitcnt vmcnt(0)" ::: "memory");
        }
        __builtin_amdgcn_s_barrier();
        bf16x8 af[4], bfr[2];
#pragma unroll
        for (int mf = 0; mf < 4; ++mf)
            af[mf] = *(const bf16x8*)((const char*)As[gbuf] +
                                      (mf * 16 + lr) * 64 + lg * 16);
#pragma unroll
        for (int nf = 0; nf < 2; ++nf)
            bfr[nf] = *(const bf16x8*)((const char*)Bs[gbuf] +
                                       (wc * 32 + nf * 16 + lr) * 64 + lg * 16);
        __builtin_amdgcn_s_setprio(1);
#pragma unroll
        for (int mf = 0; mf < 4; ++mf)
#pragma unroll
            for (int nf = 0; nf < 2; ++nf)
                acc[mf][nf] = MFMA16(af[mf], bfr[nf], acc[mf][nf]);
        __builtin_amdgcn_s_setprio(0);
        gbuf ^= 1;
    }
#undef PSTAGE
#pragma unroll
    for (int nf = 0; nf < 2; ++nf) {
        int ncol = tileN * 128 + wc * 32 + nf * 16 + lr;
        float bv = bias[ncol];
#pragma unroll
        for (int mf = 0; mf < 4; ++mf) {
            int mrow = rowBase + mf * 16 + lg * 4;
#pragma unroll
            for (int r = 0; r < 4; ++r)
                out[(size_t)(mrow + r) * 1024 + ncol] = acc[mf][nf][r] + bv;
        }
    }
}

// ---------------- flash attention v11: depth-2 prefetch (round-15 proven) -----------------
__global__ __launch_bounds__(256, 3) void attn_kernel(const bf16* __restrict__ qkv4,
                                                      const bf16* __restrict__ vt,
                                                      const int* __restrict__ mask,
                                                      bf16* __restrict__ opart,
                                                      float* __restrict__ ml) {
    __shared__ float bias_s[512];
    __shared__ bf16 Ks[3][64 * 64];
    __shared__ bf16 Vs[3][64 * 64];
    int bx = blockIdx.x;
    bx = (bx & 7) * 128 + (bx >> 3);  // XCD swizzle (1024 blocks)
    int split = bx & 3, qt = (bx >> 2) & 7, h = (bx >> 5) & 15, b = bx >> 9;
    int t = threadIdx.x;
    int wave = t >> 6, lane = t & 63, lq = lane & 31, hi = lane >> 5;
    int lq7 = lq & 7;

    const float SHIFT = 30.0f;        // constant softmax shift, log2 domain
    const int* mrow = mask + b * 2048 + split * 512;
    for (int i = t; i < 512; i += 256) bias_s[i] = mrow[i] ? -1e30f : -SHIFT;

    int qbase = qt * 128 + wave * 32;
    const bf16* qptr = qkv4 + ((size_t)(b * 1024 + qbase + lq)) * 1024 + h * 64 + hi * 8;
    bf16x8 qf[4];
#pragma unroll
    for (int s = 0; s < 4; ++s) qf[s] = *(const bf16x8*)(qptr + s * 16);

    const bf16* kpanel = qkv4 + (size_t)(2048 + b * 2048 + split * 512) * 1024 + h * 64;
    const bf16* vpanel = vt + ((size_t)((b * 16 + h) * 64)) * 2048 + split * 512;

    int r0 = t >> 3, c0 = (t & 7) ^ (r0 & 7);
    int r1 = r0 + 32, c1 = (t & 7) ^ (r1 & 7);

#define STAGE(bufi, lkn)                                                      \
    {                                                                         \
        GLD_LDS16(kpanel + (size_t)((lkn) + r0) * 1024 + c0 * 8,              \
                  (char*)Ks[bufi] + t * 16);                                  \
        GLD_LDS16(kpanel + (size_t)((lkn) + r1) * 1024 + c1 * 8,              \
                  (char*)Ks[bufi] + (t + 256) * 16);                          \
        GLD_LDS16(vpanel + (size_t)r0 * 2048 + (lkn) + c0 * 8,                \
                  (char*)Vs[bufi] + t * 16);                                  \
        GLD_LDS16(vpanel + (size_t)r1 * 2048 + (lkn) + c1 * 8,                \
                  (char*)Vs[bufi] + (t + 256) * 16);                          \
    }

    f32x16 accO0 = {}, accO1 = {};
    float l_run = 0.0f;
    const float C_QK = 0.18033688011112042f;   // 0.125 * log2(e)

#define PROCESS(bufi, s2, kloc)                                               \
    {                                                                         \
        const char* kb_ = (const char*)Ks[bufi] + ((s2) * 32 + lq) * 128;     \
        bf16x8 kf0 = *(const bf16x8*)(kb_ + (((hi + 0) ^ lq7) << 4));         \
        bf16x8 kf1 = *(const bf16x8*)(kb_ + (((hi + 2) ^ lq7) << 4));         \
        bf16x8 kf2 = *(const bf16x8*)(kb_ + (((hi + 4) ^ lq7) << 4));         \
        bf16x8 kf3 = *(const bf16x8*)(kb_ + (((hi + 6) ^ lq7) << 4));         \
        f32x16 S = {};                                                        \
        __builtin_amdgcn_s_setprio(1);                                        \
        S = MFMA32(kf0, qf[0], S);                                            \
        S = MFMA32(kf1, qf[1], S);                                            \
        S = MFMA32(kf2, qf[2], S);                                            \
        S = MFMA32(kf3, qf[3], S);                                            \
        __builtin_amdgcn_s_setprio(0);                                        \
        f32x4 bv0 = *(const f32x4*)&bias_s[(kloc) + 4 * hi];                  \
        f32x4 bv1 = *(const f32x4*)&bias_s[(kloc) + 8 + 4 * hi];              \
        f32x4 bv2 = *(const f32x4*)&bias_s[(kloc) + 16 + 4 * hi];             \
        f32x4 bv3 = *(const f32x4*)&bias_s[(kloc) + 24 + 4 * hi];             \
        float p[16];                                                          \
        _Pragma("unroll")                                                     \
        for (int r = 0; r < 16; ++r) {                                        \
            float bvr = (r < 4 ? bv0[r & 3] : r < 8 ? bv1[r & 3]              \
                         : r < 12 ? bv2[r & 3] : bv3[r & 3]);                 \
            p[r] = __builtin_amdgcn_exp2f(fmaf(S[r], C_QK, bvr));             \
        }                                                                     \
        l_run += ((p[0] + p[1]) + (p[2] + p[3])) + ((p[4] + p[5]) + (p[6] + p[7])) \
               + ((p[8] + p[9]) + (p[10] + p[11])) + ((p[12] + p[13]) + (p[14] + p[15])); \
        union { unsigned u[4]; bf16x8 v; } pf0, pf1;                          \
        _Pragma("unroll")                                                     \
        for (int w = 0; w < 4; ++w) {                                         \
            union { bf16x2 h2; unsigned u; } cv;                              \
            cv.h2[0] = (bf16)p[2 * w]; cv.h2[1] = (bf16)p[2 * w + 1];         \
            pf0.u[w] = cv.u;                                                  \
            cv.h2[0] = (bf16)p[8 + 2 * w]; cv.h2[1] = (bf16)p[9 + 2 * w];     \
            pf1.u[w] = cv.u;                                                  \
        }                                                                     \
        const char* vbA = (const char*)Vs[bufi] + lq * 128 + hi * 8;          \
        const char* vbB = vbA + 32 * 128;                                     \
        bf16x4 va[8];                                                         \
        _Pragma("unroll")                                                     \
        for (int m = 0; m < 4; ++m) {                                         \
            int cofs = ((((s2) * 4 + m) ^ lq7) << 4);                         \
            va[m] = *(const bf16x4*)(vbA + cofs);                             \
            va[4 + m] = *(const bf16x4*)(vbB + cofs);                         \
        }                                                                     \
        bf16x8 va0 = __builtin_shufflevector(va[0], va[1], 0, 1, 2, 3, 4, 5, 6, 7); \
        bf16x8 va1 = __builtin_shufflevector(va[2], va[3], 0, 1, 2, 3, 4, 5, 6, 7); \
        bf16x8 va2 = __builtin_shufflevector(va[4], va[5], 0, 1, 2, 3, 4, 5, 6, 7); \
        bf16x8 va3 = __builtin_shufflevector(va[6], va[7], 0, 1, 2, 3, 4, 5, 6, 7); \
        __builtin_amdgcn_s_setprio(1);                                        \
        accO0 = MFMA32(va0, pf0.v, accO0);                                    \
        accO0 = MFMA32(va1, pf1.v, accO0);                                    \
        accO1 = MFMA32(va2, pf0.v, accO1);                                    \
        accO1 = MFMA32(va3, pf1.v, accO1);                                    \
        __builtin_amdgcn_s_setprio(0);                                        \
    }

    STAGE(0, 0);
    __syncthreads();   // prologue drain: tile0 + bias_s visible to all waves
    STAGE(1, 64);      // tile1 in flight across the loop entry
#pragma unroll
    for (int it = 0; it < 8; ++it) {
        __builtin_amdgcn_s_barrier();   // readers of tile it-1 retired (its buffer is reused)
        if (it + 2 < 8) {
            STAGE((it + 2) % 3, (it + 2) * 64);
            asm volatile("s_waitcnt vmcnt(8)" ::: "memory");   // tile it landed (2 in flight)
        } else if (it == 6) {
            asm volatile("s_waitcnt vmcnt(4)" ::: "memory");
        } else {
            asm volatile("s_waitcnt vmcnt(0)" ::: "memory");
        }
        __builtin_amdgcn_s_barrier();   // every wave's current-tile loads landed
        PROCESS(it % 3, 0, it * 64);
        PROCESS(it % 3, 1, it * 64 + 32);
    }
#undef STAGE
#undef PROCESS

    l_run += __shfl_xor(l_run, 32);

    float linv = (l_run > 0.0f) ? (1.0f / l_run) : 0.0f;
    size_t orow = (size_t)(split * 2048 + b * 1024 + qbase + lq);
    bf16* op = opart + orow * 1024 + h * 64;
#pragma unroll
    for (int m = 0; m < 4; ++m) {
        bf16x4 y0, y1;
#pragma unroll
        for (int r = 0; r < 4; ++r) {
            y0[r] = (bf16)(accO0[4 * m + r] * linv);
            y1[r] = (bf16)(accO1[4 * m + r] * linv);
        }
        *(bf16x4*)(op + 8 * m + 4 * hi) = y0;
        *(bf16x4*)(op + 32 + 8 * m + 4 * hi) = y1;
    }
    if (lane < 32) {
        float2 mlv = {SHIFT, l_run};
        *(float2*)(ml + (orow * 16 + h) * 2) = mlv;
    }
}

// ---------------- combine 4 splits -> attn_out bf16 (m in log2 domain) ----------------
__global__ __launch_bounds__(256) void combine_kernel(const bf16* __restrict__ opart,
                                                      const float* __restrict__ ml,
                                                      bf16* __restrict__ out) {
    int row = blockIdx.x;          // b*1024 + q
    int t = threadIdx.x;
    int h = t >> 4;
    float m[4], l[4];
#pragma unroll
    for (int s = 0; s < 4; ++s) {
        const float* p = ml + ((size_t)(s * 2048 + row) * 16 + h) * 2;
        m[s] = p[0]; l[s] = p[1];
    }
    float M = fmaxf(fmaxf(m[0], m[1]), fmaxf(m[2], m[3]));
    float u[4], denom = 0.0f;
#pragma unroll
    for (int s = 0; s < 4; ++s) { u[s] = exp2f(m[s] - M) * l[s]; denom += u[s]; }
    float inv = (denom > 0.0f) ? (1.0f / denom) : 0.0f;
    float acc[4] = {0.f, 0.f, 0.f, 0.f};
#pragma unroll
    for (int s = 0; s < 4; ++s) {
        bf16x4 y = *(const bf16x4*)(opart + (size_t)(s * 2048 + row) * 1024 + t * 4);
#pragma unroll
        for (int c = 0; c < 4; ++c) acc[c] += u[s] * (float)y[c];
    }
    bf16x4 r;
#pragma unroll
    for (int c = 0; c < 4; ++c) r[c] = (bf16)(acc[c] * inv);
    *(bf16x4*)(out + (size_t)row * 1024 + t * 4) = r;
}

extern "C" void kernel_launch(void* const* d_in, const int* in_sizes, int n_in,
                              void* d_out, int out_size, void* d_ws, size_t ws_size,
                              hipStream_t stream) {
    const float* q    = (const float*)d_in[0];
    const float* k    = (const float*)d_in[1];
    const float* v    = (const float*)d_in[2];
    const float* qpos = (const float*)d_in[3];
    const float* kpos = (const float*)d_in[4];
    const int*   mask = (const int*)d_in[5];
    const float* lnqw = (const float*)d_in[6];
    const float* lnqb = (const float*)d_in[7];
    const float* lnkw = (const float*)d_in[8];
    const float* lnkb = (const float*)d_in[9];
    const float* lnvw = (const float*)d_in[10];
    const float* lnvb = (const float*)d_in[11];
    const float* wq   = (const float*)d_in[12];
    const float* wk   = (const float*)d_in[13];
    const float* wv   = (const float*)d_in[14];
    const float* wp   = (const float*)d_in[15];
    const float* bp   = (const float*)d_in[16];
    float* out = (float*)d_out;

    char* ws = (char*)d_ws;
    const size_t MB = 1024 * 1024;
    // layout:
    //  0- 2 wq_b, 2-4 wk_b, 4-6 wv_b (dead after gemm1), 6-8 wp_b (live to gemm2)
    //  0- 4: attn_out bf16 [2048][1024] (overlays dead wq_b/wk_b)
    //  8-24: opart bf16 [4][2048][1024] normalized partials (overlays dead xn)
    //  8-28: xn bf16 [10240][1024]      (dead after gemm1)
    // 24-25: ml f32 [4][2048][16][2]
    // 28-40: qkv4 bf16 [6144][1024]
    // 40-48: Vt bf16 [2][16][64][2048]
    bf16*  w_all = (bf16*)(ws + 0 * MB);
    bf16*  wq_b  = (bf16*)(ws + 0 * MB);
    bf16*  wk_b  = (bf16*)(ws + 2 * MB);
    bf16*  wv_b  = (bf16*)(ws + 4 * MB);
    bf16*  wp_b  = (bf16*)(ws + 6 * MB);
    bf16*  xn    = (bf16*)(ws + 8 * MB);
    bf16*  opart = (bf16*)(ws + 8 * MB);
    float* mlbuf = (float*)(ws + 24 * MB);
    bf16*  qkv4  = (bf16*)(ws + 28 * MB);
    bf16*  vtb   = (bf16*)(ws + 40 * MB);
    bf16*  attn  = (bf16*)(ws + 0 * MB);

    prep_all<<<14336, 256, 0, stream>>>(wq, wk, wv, wp, w_all,
                                        q, k, v, qpos, kpos,
                                        lnqw, lnqb, lnkw, lnkb, lnvw, lnvb, xn);

    // QKV projection; v-rows written transposed to Vt. BM=128, BK=64, swizzled staging.
    gemm_qkv<<<640, 256, 0, stream>>>(xn, wq_b, wk_b, wv_b, qkv4, vtb);

    attn_kernel<<<1024, 256, 0, stream>>>(qkv4, vtb, mask, opart, mlbuf);

    combine_kernel<<<2048, 256, 0, stream>>>(opart, mlbuf, attn);

    gemm_proj<<<256, 256, 0, stream>>>(attn, wp_b, bp, out);
}

// Round 17
// 108.335 us; speedup vs baseline: 1.0681x; 1.0681x over previous
//
#include <hip/hip_runtime.h>
#include <stdint.h>
#include <stddef.h>

typedef __bf16 bf16;
typedef bf16 bf16x2 __attribute__((ext_vector_type(2)));
typedef bf16 bf16x4 __attribute__((ext_vector_type(4)));
typedef bf16 bf16x8 __attribute__((ext_vector_type(8)));
typedef float f32x4 __attribute__((ext_vector_type(4)));
typedef float f32x16 __attribute__((ext_vector_type(16)));

#define MFMA16(a, b, c) __builtin_amdgcn_mfma_f32_16x16x32_bf16((a), (b), (c), 0, 0, 0)
#define MFMA32(a, b, c) __builtin_amdgcn_mfma_f32_32x32x16_bf16((a), (b), (c), 0, 0, 0)

// async global->LDS, 16B per lane, dest = wave-uniform base + lane*16
#define GLD_LDS16(g, l)                                          \
    __builtin_amdgcn_global_load_lds(                            \
        (const __attribute__((address_space(1))) void*)(g),      \
        (__attribute__((address_space(3))) void*)(l), 16, 0, 0)

// ---------------- fused (weights cast | pos-add + LayerNorm + cast) ----------------
__global__ __launch_bounds__(256) void prep_all(const float* __restrict__ wq,
                                                const float* __restrict__ wk,
                                                const float* __restrict__ wv,
                                                const float* __restrict__ wp,
                                                bf16* __restrict__ wout,
                                                const float* __restrict__ q,
                                                const float* __restrict__ k,
                                                const float* __restrict__ v,
                                                const float* __restrict__ qpos,
                                                const float* __restrict__ kpos,
                                                const float* __restrict__ lnqw,
                                                const float* __restrict__ lnqb,
                                                const float* __restrict__ lnkw,
                                                const float* __restrict__ lnkb,
                                                const float* __restrict__ lnvw,
                                                const float* __restrict__ lnvb,
                                                bf16* __restrict__ out) {
    int bx = blockIdx.x;
    int t = threadIdx.x;
    if (bx < 4096) {
        int i = (bx * 256 + t) * 4;
        const float* src;
        int j = i;
        if (i < (1 << 20)) { src = wq; }
        else if (i < (2 << 20)) { src = wk; j = i - (1 << 20); }
        else if (i < (3 << 20)) { src = wv; j = i - (2 << 20); }
        else { src = wp; j = i - (3 << 20); }
        float4 vv = *(const float4*)(src + j);
        bf16x4 o;
        o[0] = (bf16)vv.x; o[1] = (bf16)vv.y; o[2] = (bf16)vv.z; o[3] = (bf16)vv.w;
        *(bf16x4*)(wout + i) = o;
        return;
    }
    int row = bx - 4096;
    const float *x, *pos, *w, *bb;
    int r = row;
    if (row < 2048)      { x = q; pos = qpos; w = lnqw; bb = lnqb; }
    else if (row < 6144) { r = row - 2048; x = k; pos = kpos; w = lnkw; bb = lnkb; }
    else                 { r = row - 6144; x = v; pos = nullptr; w = lnvw; bb = lnvb; }

    float4 vv = ((const float4*)(x + (size_t)r * 1024))[t];
    if (pos != nullptr) {
        float4 p = ((const float4*)(pos + (size_t)r * 1024))[t];
        vv.x += p.x; vv.y += p.y; vv.z += p.z; vv.w += p.w;
    }
    float s1 = vv.x + vv.y + vv.z + vv.w;
    float s2 = vv.x * vv.x + vv.y * vv.y + vv.z * vv.z + vv.w * vv.w;
#pragma unroll
    for (int off = 1; off < 64; off <<= 1) {
        s1 += __shfl_xor(s1, off);
        s2 += __shfl_xor(s2, off);
    }
    __shared__ float red[8];
    int wave = t >> 6;
    if ((t & 63) == 0) { red[wave * 2] = s1; red[wave * 2 + 1] = s2; }
    __syncthreads();
    s1 = red[0] + red[2] + red[4] + red[6];
    s2 = red[1] + red[3] + red[5] + red[7];
    float mu = s1 * (1.0f / 1024.0f);
    float var = s2 * (1.0f / 1024.0f) - mu * mu;
    float rstd = rsqrtf(var + 1e-5f);
    float4 wv4 = ((const float4*)w)[t];
    float4 bv4 = ((const float4*)bb)[t];
    bf16x4 o;
    o[0] = (bf16)((vv.x - mu) * rstd * wv4.x + bv4.x);
    o[1] = (bf16)((vv.y - mu) * rstd * wv4.y + bv4.y);
    o[2] = (bf16)((vv.z - mu) * rstd * wv4.z + bv4.z);
    o[3] = (bf16)((vv.w - mu) * rstd * wv4.w + bv4.w);
    *(bf16x4*)(out + (size_t)row * 1024 + t * 4) = o;
}

// ---------------- gemm1 (QKV): BM=128, BK=32, XOR-swizzled staging, counted vmcnt ---------
// Round-13 proven shell (32 KB LDS -> high occupancy) + conflict-free fragment reads:
// chunk swizzle cc = c ^ ((row>>1)&3). Read slot (row&1, lg^((lr>>1)&3)) covers all
// 8 bank-slots over 16 lanes -> 2-way (free). Swizzle cancels via pre-swizzled global
// source (T21 both-sides).
__global__ __launch_bounds__(256) void gemm_qkv(const bf16* __restrict__ A,
                                                const bf16* __restrict__ w0,
                                                const bf16* __restrict__ w1,
                                                const bf16* __restrict__ w2,
                                                bf16* __restrict__ out,
                                                bf16* __restrict__ vt) {
    __shared__ bf16 As[2][128 * 32];
    __shared__ bf16 Bs[2][128 * 32];
    int bxr = blockIdx.x;
    int bx = (bxr & 7) * 80 + (bxr >> 3);   // XCD swizzle (640 blocks)
    int tileN = bx & 7;
    int tileM = bx >> 3;
    int t = threadIdx.x;
    int wave = t >> 6, lane = t & 63;
    int lr = lane & 15, lg = lane >> 4;
    int wr = wave >> 1, wc = wave & 1;
    int co = (lg ^ ((lr >> 1) & 3)) << 4;   // fragment-read chunk byte offset (row base %16==0)
    int rowBase = tileM * 128;
    const bf16* W = (rowBase < 2048) ? w0 : ((rowBase < 6144) ? w1 : w2);
    const bf16* Ab = A + (size_t)rowBase * 1024;
    const bf16* Wb = W + (size_t)(tileN * 128) * 1024;

    // staging: chunk o in 0..511 (128 rows x 4 chunks of 16B); swz cc = (o&3)^((row>>1)&3)
    int o0 = t, o1 = t + 256;
    int sr0 = o0 >> 2, sc0 = (o0 & 3) ^ ((sr0 >> 1) & 3);
    int sr1 = o1 >> 2, sc1 = (o1 & 3) ^ ((sr1 >> 1) & 3);

#define QSTAGE(bufi, k0n)                                                     \
    {                                                                         \
        GLD_LDS16(Ab + (size_t)sr0 * 1024 + (k0n) + sc0 * 8,                  \
                  (char*)As[bufi] + o0 * 16);                                 \
        GLD_LDS16(Ab + (size_t)sr1 * 1024 + (k0n) + sc1 * 8,                  \
                  (char*)As[bufi] + o1 * 16);                                 \
        GLD_LDS16(Wb + (size_t)sr0 * 1024 + (k0n) + sc0 * 8,                  \
                  (char*)Bs[bufi] + o0 * 16);                                 \
        GLD_LDS16(Wb + (size_t)sr1 * 1024 + (k0n) + sc1 * 8,                  \
                  (char*)Bs[bufi] + o1 * 16);                                 \
    }

    const f32x4 zero4 = {0.f, 0.f, 0.f, 0.f};
    f32x4 acc[4][4];
#pragma unroll
    for (int i = 0; i < 4; ++i)
#pragma unroll
        for (int j = 0; j < 4; ++j) acc[i][j] = zero4;

    QSTAGE(0, 0);
    __syncthreads();   // prologue drain
    int gbuf = 0;
    for (int k0 = 0; k0 < 1024; k0 += 32) {
        __builtin_amdgcn_s_barrier();   // all waves done reading gbuf^1 (prev iter)
        if (k0 + 32 < 1024) {
            QSTAGE(gbuf ^ 1, k0 + 32);
            asm volatile("s_waitcnt vmcnt(4)" ::: "memory");
        } else {
            asm volatile("s_waitcnt vmcnt(0)" ::: "memory");
        }
        __builtin_amdgcn_s_barrier();   // current-tile loads landed everywhere
        bf16x8 af[4], bfr[4];
#pragma unroll
        for (int mf = 0; mf < 4; ++mf)
            af[mf] = *(const bf16x8*)((const char*)As[gbuf] +
                                      (wr * 64 + mf * 16 + lr) * 64 + co);
#pragma unroll
        for (int nf = 0; nf < 4; ++nf)
            bfr[nf] = *(const bf16x8*)((const char*)Bs[gbuf] +
                                       (wc * 64 + nf * 16 + lr) * 64 + co);
        __builtin_amdgcn_s_setprio(1);
#pragma unroll
        for (int mf = 0; mf < 4; ++mf)
#pragma unroll
            for (int nf = 0; nf < 4; ++nf)
                acc[mf][nf] = MFMA16(af[mf], bfr[nf], acc[mf][nf]);
        __builtin_amdgcn_s_setprio(0);
        gbuf ^= 1;
    }
#undef QSTAGE
    bool isV = (rowBase >= 6144);
    if (!isV) {
#pragma unroll
        for (int nf = 0; nf < 4; ++nf) {
            int ncol = tileN * 128 + wc * 64 + nf * 16 + lr;
#pragma unroll
            for (int mf = 0; mf < 4; ++mf) {
                int mrow = rowBase + wr * 64 + mf * 16 + lg * 4;
#pragma unroll
                for (int r = 0; r < 4; ++r)
                    out[(size_t)(mrow + r) * 1024 + ncol] = (bf16)acc[mf][nf][r];
            }
        }
    } else {
        int b2 = (rowBase - 6144) >> 11;
        int kb = rowBase - 6144 - (b2 << 11);
#pragma unroll
        for (int nf = 0; nf < 4; ++nf) {
            int ncol = tileN * 128 + wc * 64 + nf * 16 + lr;
            int h2 = ncol >> 6, d2 = ncol & 63;
            bf16* vrow = vt + ((size_t)((b2 * 16 + h2) * 64 + d2)) * 2048;
#pragma unroll
            for (int mf = 0; mf < 4; ++mf) {
                int kk = kb + wr * 64 + mf * 16 + lg * 4;
                bf16x4 pv;
#pragma unroll
                for (int r = 0; r < 4; ++r) pv[r] = (bf16)acc[mf][nf][r];
                *(bf16x4*)(vrow + kk) = pv;
            }
        }
    }
}

// ---------------- gemm2 (proj): BM=64, BK=32, counted-vmcnt (round-13 proven) -------------
__global__ __launch_bounds__(256) void gemm_proj(const bf16* __restrict__ A,
                                                 const bf16* __restrict__ w0,
                                                 const float* __restrict__ bias,
                                                 float* __restrict__ out) {
    __shared__ bf16 As[2][64 * 32];
    __shared__ bf16 Bs[2][128 * 32];
    int bxr = blockIdx.x;
    int bx = (bxr & 7) * 32 + (bxr >> 3);   // XCD swizzle (256 blocks)
    int tileN = bx & 7;
    int tileM = bx >> 3;
    int t = threadIdx.x;
    int wave = t >> 6, lane = t & 63;
    int lr = lane & 15, lg = lane >> 4;
    int wc = wave;
    int rowBase = tileM * 64;
    const bf16* Ab = A + (size_t)rowBase * 1024;
    const bf16* Wb = w0 + (size_t)(tileN * 128) * 1024;

    int o16b0 = wave * 128 + lane;
    int o16b1 = o16b0 + 64;

#define PSTAGE(bufi, k0n)                                                     \
    {                                                                         \
        GLD_LDS16(Ab + (size_t)(t >> 2) * 1024 + (k0n) + (t & 3) * 8,         \
                  (char*)As[bufi] + t * 16);                                  \
        GLD_LDS16(Wb + (size_t)(o16b0 >> 2) * 1024 + (k0n) + (o16b0 & 3) * 8, \
                  (char*)Bs[bufi] + o16b0 * 16);                              \
        GLD_LDS16(Wb + (size_t)(o16b1 >> 2) * 1024 + (k0n) + (o16b1 & 3) * 8, \
                  (char*)Bs[bufi] + o16b1 * 16);                              \
    }

    const f32x4 zero4 = {0.f, 0.f, 0.f, 0.f};
    f32x4 acc[4][2];
#pragma unroll
    for (int i = 0; i < 4; ++i) { acc[i][0] = zero4; acc[i][1] = zero4; }

    PSTAGE(0, 0);
    __syncthreads();
    int gbuf = 0;
    for (int k0 = 0; k0 < 1024; k0 += 32) {
        __builtin_amdgcn_s_barrier();
        if (k0 + 32 < 1024) {
            PSTAGE(gbuf ^ 1, k0 + 32);
            asm volatile("s_waitcnt vmcnt(3)" ::: "memory");
        } else {
            asm volatile("s_waitcnt vmcnt(0)" ::: "memory");
        }
        __builtin_amdgcn_s_barrier();
        bf16x8 af[4], bfr[2];
#pragma unroll
        for (int mf = 0; mf < 4; ++mf)
            af[mf] = *(const bf16x8*)((const char*)As[gbuf] +
                                      (mf * 16 + lr) * 64 + lg * 16);
#pragma unroll
        for (int nf = 0; nf < 2; ++nf)
            bfr[nf] = *(const bf16x8*)((const char*)Bs[gbuf] +
                                       (wc * 32 + nf * 16 + lr) * 64 + lg * 16);
        __builtin_amdgcn_s_setprio(1);
#pragma unroll
        for (int mf = 0; mf < 4; ++mf)
#pragma unroll
            for (int nf = 0; nf < 2; ++nf)
                acc[mf][nf] = MFMA16(af[mf], bfr[nf], acc[mf][nf]);
        __builtin_amdgcn_s_setprio(0);
        gbuf ^= 1;
    }
#undef PSTAGE
#pragma unroll
    for (int nf = 0; nf < 2; ++nf) {
        int ncol = tileN * 128 + wc * 32 + nf * 16 + lr;
        float bv = bias[ncol];
#pragma unroll
        for (int mf = 0; mf < 4; ++mf) {
            int mrow = rowBase + mf * 16 + lg * 4;
#pragma unroll
            for (int r = 0; r < 4; ++r)
                out[(size_t)(mrow + r) * 1024 + ncol] = acc[mf][nf][r] + bv;
        }
    }
}

// ---------------- flash attention v11: depth-2 prefetch (round-15 proven) -----------------
__global__ __launch_bounds__(256, 3) void attn_kernel(const bf16* __restrict__ qkv4,
                                                      const bf16* __restrict__ vt,
                                                      const int* __restrict__ mask,
                                                      bf16* __restrict__ opart,
                                                      float* __restrict__ ml) {
    __shared__ float bias_s[512];
    __shared__ bf16 Ks[3][64 * 64];
    __shared__ bf16 Vs[3][64 * 64];
    int bx = blockIdx.x;
    bx = (bx & 7) * 128 + (bx >> 3);  // XCD swizzle (1024 blocks)
    int split = bx & 3, qt = (bx >> 2) & 7, h = (bx >> 5) & 15, b = bx >> 9;
    int t = threadIdx.x;
    int wave = t >> 6, lane = t & 63, lq = lane & 31, hi = lane >> 5;
    int lq7 = lq & 7;

    const float SHIFT = 30.0f;        // constant softmax shift, log2 domain
    const int* mrow = mask + b * 2048 + split * 512;
    for (int i = t; i < 512; i += 256) bias_s[i] = mrow[i] ? -1e30f : -SHIFT;

    int qbase = qt * 128 + wave * 32;
    const bf16* qptr = qkv4 + ((size_t)(b * 1024 + qbase + lq)) * 1024 + h * 64 + hi * 8;
    bf16x8 qf[4];
#pragma unroll
    for (int s = 0; s < 4; ++s) qf[s] = *(const bf16x8*)(qptr + s * 16);

    const bf16* kpanel = qkv4 + (size_t)(2048 + b * 2048 + split * 512) * 1024 + h * 64;
    const bf16* vpanel = vt + ((size_t)((b * 16 + h) * 64)) * 2048 + split * 512;

    int r0 = t >> 3, c0 = (t & 7) ^ (r0 & 7);
    int r1 = r0 + 32, c1 = (t & 7) ^ (r1 & 7);

#define STAGE(bufi, lkn)                                                      \
    {                                                                         \
        GLD_LDS16(kpanel + (size_t)((lkn) + r0) * 1024 + c0 * 8,              \
                  (char*)Ks[bufi] + t * 16);                                  \
        GLD_LDS16(kpanel + (size_t)((lkn) + r1) * 1024 + c1 * 8,              \
                  (char*)Ks[bufi] + (t + 256) * 16);                          \
        GLD_LDS16(vpanel + (size_t)r0 * 2048 + (lkn) + c0 * 8,                \
                  (char*)Vs[bufi] + t * 16);                                  \
        GLD_LDS16(vpanel + (size_t)r1 * 2048 + (lkn) + c1 * 8,                \
                  (char*)Vs[bufi] + (t + 256) * 16);                          \
    }

    f32x16 accO0 = {}, accO1 = {};
    float l_run = 0.0f;
    const float C_QK = 0.18033688011112042f;   // 0.125 * log2(e)

#define PROCESS(bufi, s2, kloc)                                               \
    {                                                                         \
        const char* kb_ = (const char*)Ks[bufi] + ((s2) * 32 + lq) * 128;     \
        bf16x8 kf0 = *(const bf16x8*)(kb_ + (((hi + 0) ^ lq7) << 4));         \
        bf16x8 kf1 = *(const bf16x8*)(kb_ + (((hi + 2) ^ lq7) << 4));         \
        bf16x8 kf2 = *(const bf16x8*)(kb_ + (((hi + 4) ^ lq7) << 4));         \
        bf16x8 kf3 = *(const bf16x8*)(kb_ + (((hi + 6) ^ lq7) << 4));         \
        f32x16 S = {};                                                        \
        __builtin_amdgcn_s_setprio(1);                                        \
        S = MFMA32(kf0, qf[0], S);                                            \
        S = MFMA32(kf1, qf[1], S);                                            \
        S = MFMA32(kf2, qf[2], S);                                            \
        S = MFMA32(kf3, qf[3], S);                                            \
        __builtin_amdgcn_s_setprio(0);                                        \
        f32x4 bv0 = *(const f32x4*)&bias_s[(kloc) + 4 * hi];                  \
        f32x4 bv1 = *(const f32x4*)&bias_s[(kloc) + 8 + 4 * hi];              \
        f32x4 bv2 = *(const f32x4*)&bias_s[(kloc) + 16 + 4 * hi];             \
        f32x4 bv3 = *(const f32x4*)&bias_s[(kloc) + 24 + 4 * hi];             \
        float p[16];                                                          \
        _Pragma("unroll")                                                     \
        for (int r = 0; r < 16; ++r) {                                        \
            float bvr = (r < 4 ? bv0[r & 3] : r < 8 ? bv1[r & 3]              \
                         : r < 12 ? bv2[r & 3] : bv3[r & 3]);                 \
            p[r] = __builtin_amdgcn_exp2f(fmaf(S[r], C_QK, bvr));             \
        }                                                                     \
        l_run += ((p[0] + p[1]) + (p[2] + p[3])) + ((p[4] + p[5]) + (p[6] + p[7])) \
               + ((p[8] + p[9]) + (p[10] + p[11])) + ((p[12] + p[13]) + (p[14] + p[15])); \
        union { unsigned u[4]; bf16x8 v; } pf0, pf1;                          \
        _Pragma("unroll")                                                     \
        for (int w = 0; w < 4; ++w) {                                         \
            union { bf16x2 h2; unsigned u; } cv;                              \
            cv.h2[0] = (bf16)p[2 * w]; cv.h2[1] = (bf16)p[2 * w + 1];         \
            pf0.u[w] = cv.u;                                                  \
            cv.h2[0] = (bf16)p[8 + 2 * w]; cv.h2[1] = (bf16)p[9 + 2 * w];     \
            pf1.u[w] = cv.u;                                                  \
        }                                                                     \
        const char* vbA = (const char*)Vs[bufi] + lq * 128 + hi * 8;          \
        const char* vbB = vbA + 32 * 128;                                     \
        bf16x4 va[8];                                                         \
        _Pragma("unroll")                                                     \
        for (int m = 0; m < 4; ++m) {                                         \
            int cofs = ((((s2) * 4 + m) ^ lq7) << 4);                         \
            va[m] = *(const bf16x4*)(vbA + cofs);                             \
            va[4 + m] = *(const bf16x4*)(vbB + cofs);                         \
        }                                                                     \
        bf16x8 va0 = __builtin_shufflevector(va[0], va[1], 0, 1, 2, 3, 4, 5, 6, 7); \
        bf16x8 va1 = __builtin_shufflevector(va[2], va[3], 0, 1, 2, 3, 4, 5, 6, 7); \
        bf16x8 va2 = __builtin_shufflevector(va[4], va[5], 0, 1, 2, 3, 4, 5, 6, 7); \
        bf16x8 va3 = __builtin_shufflevector(va[6], va[7], 0, 1, 2, 3, 4, 5, 6, 7); \
        __builtin_amdgcn_s_setprio(1);                                        \
        accO0 = MFMA32(va0, pf0.v, accO0);                                    \
        accO0 = MFMA32(va1, pf1.v, accO0);                                    \
        accO1 = MFMA32(va2, pf0.v, accO1);                                    \
        accO1 = MFMA32(va3, pf1.v, accO1);                                    \
        __builtin_amdgcn_s_setprio(0);                                        \
    }

    STAGE(0, 0);
    __syncthreads();   // prologue drain: tile0 + bias_s visible to all waves
    STAGE(1, 64);      // tile1 in flight across the loop entry
#pragma unroll
    for (int it = 0; it < 8; ++it) {
        __builtin_amdgcn_s_barrier();   // readers of tile it-1 retired (its buffer is reused)
        if (it + 2 < 8) {
            STAGE((it + 2) % 3, (it + 2) * 64);
            asm volatile("s_waitcnt vmcnt(8)" ::: "memory");   // tile it landed (2 in flight)
        } else if (it == 6) {
            asm volatile("s_waitcnt vmcnt(4)" ::: "memory");
        } else {
            asm volatile("s_waitcnt vmcnt(0)" ::: "memory");
        }
        __builtin_amdgcn_s_barrier();   // every wave's current-tile loads landed
        PROCESS(it % 3, 0, it * 64);
        PROCESS(it % 3, 1, it * 64 + 32);
    }
#undef STAGE
#undef PROCESS

    l_run += __shfl_xor(l_run, 32);

    float linv = (l_run > 0.0f) ? (1.0f / l_run) : 0.0f;
    size_t orow = (size_t)(split * 2048 + b * 1024 + qbase + lq);
    bf16* op = opart + orow * 1024 + h * 64;
#pragma unroll
    for (int m = 0; m < 4; ++m) {
        bf16x4 y0, y1;
#pragma unroll
        for (int r = 0; r < 4; ++r) {
            y0[r] = (bf16)(accO0[4 * m + r] * linv);
            y1[r] = (bf16)(accO1[4 * m + r] * linv);
        }
        *(bf16x4*)(op + 8 * m + 4 * hi) = y0;
        *(bf16x4*)(op + 32 + 8 * m + 4 * hi) = y1;
    }
    if (lane < 32) {
        float2 mlv = {SHIFT, l_run};
        *(float2*)(ml + (orow * 16 + h) * 2) = mlv;
    }
}

// ---------------- combine 4 splits -> attn_out bf16 (m in log2 domain) ----------------
__global__ __launch_bounds__(256) void combine_kernel(const bf16* __restrict__ opart,
                                                      const float* __restrict__ ml,
                                                      bf16* __restrict__ out) {
    int row = blockIdx.x;          // b*1024 + q
    int t = threadIdx.x;
    int h = t >> 4;
    float m[4], l[4];
#pragma unroll
    for (int s = 0; s < 4; ++s) {
        const float* p = ml + ((size_t)(s * 2048 + row) * 16 + h) * 2;
        m[s] = p[0]; l[s] = p[1];
    }
    float M = fmaxf(fmaxf(m[0], m[1]), fmaxf(m[2], m[3]));
    float u[4], denom = 0.0f;
#pragma unroll
    for (int s = 0; s < 4; ++s) { u[s] = exp2f(m[s] - M) * l[s]; denom += u[s]; }
    float inv = (denom > 0.0f) ? (1.0f / denom) : 0.0f;
    float acc[4] = {0.f, 0.f, 0.f, 0.f};
#pragma unroll
    for (int s = 0; s < 4; ++s) {
        bf16x4 y = *(const bf16x4*)(opart + (size_t)(s * 2048 + row) * 1024 + t * 4);
#pragma unroll
        for (int c = 0; c < 4; ++c) acc[c] += u[s] * (float)y[c];
    }
    bf16x4 r;
#pragma unroll
    for (int c = 0; c < 4; ++c) r[c] = (bf16)(acc[c] * inv);
    *(bf16x4*)(out + (size_t)row * 1024 + t * 4) = r;
}

extern "C" void kernel_launch(void* const* d_in, const int* in_sizes, int n_in,
                              void* d_out, int out_size, void* d_ws, size_t ws_size,
                              hipStream_t stream) {
    const float* q    = (const float*)d_in[0];
    const float* k    = (const float*)d_in[1];
    const float* v    = (const float*)d_in[2];
    const float* qpos = (const float*)d_in[3];
    const float* kpos = (const float*)d_in[4];
    const int*   mask = (const int*)d_in[5];
    const float* lnqw = (const float*)d_in[6];
    const float* lnqb = (const float*)d_in[7];
    const float* lnkw = (const float*)d_in[8];
    const float* lnkb = (const float*)d_in[9];
    const float* lnvw = (const float*)d_in[10];
    const float* lnvb = (const float*)d_in[11];
    const float* wq   = (const float*)d_in[12];
    const float* wk   = (const float*)d_in[13];
    const float* wv   = (const float*)d_in[14];
    const float* wp   = (const float*)d_in[15];
    const float* bp   = (const float*)d_in[16];
    float* out = (float*)d_out;

    char* ws = (char*)d_ws;
    const size_t MB = 1024 * 1024;
    // layout:
    //  0- 2 wq_b, 2-4 wk_b, 4-6 wv_b (dead after gemm1), 6-8 wp_b (live to gemm2)
    //  0- 4: attn_out bf16 [2048][1024] (overlays dead wq_b/wk_b)
    //  8-24: opart bf16 [4][2048][1024] normalized partials (overlays dead xn)
    //  8-28: xn bf16 [10240][1024]      (dead after gemm1)
    // 24-25: ml f32 [4][2048][16][2]
    // 28-40: qkv4 bf16 [6144][1024]
    // 40-48: Vt bf16 [2][16][64][2048]
    bf16*  w_all = (bf16*)(ws + 0 * MB);
    bf16*  wq_b  = (bf16*)(ws + 0 * MB);
    bf16*  wk_b  = (bf16*)(ws + 2 * MB);
    bf16*  wv_b  = (bf16*)(ws + 4 * MB);
    bf16*  wp_b  = (bf16*)(ws + 6 * MB);
    bf16*  xn    = (bf16*)(ws + 8 * MB);
    bf16*  opart = (bf16*)(ws + 8 * MB);
    float* mlbuf = (float*)(ws + 24 * MB);
    bf16*  qkv4  = (bf16*)(ws + 28 * MB);
    bf16*  vtb   = (bf16*)(ws + 40 * MB);
    bf16*  attn  = (bf16*)(ws + 0 * MB);

    prep_all<<<14336, 256, 0, stream>>>(wq, wk, wv, wp, w_all,
                                        q, k, v, qpos, kpos,
                                        lnqw, lnqb, lnkw, lnkb, lnvw, lnvb, xn);

    // QKV projection; v-rows written transposed to Vt. BM=128, BK=32, swizzled staging.
    gemm_qkv<<<640, 256, 0, stream>>>(xn, wq_b, wk_b, wv_b, qkv4, vtb);

    attn_kernel<<<1024, 256, 0, stream>>>(qkv4, vtb, mask, opart, mlbuf);

    combine_kernel<<<2048, 256, 0, stream>>>(opart, mlbuf, attn);

    gemm_proj<<<256, 256, 0, stream>>>(attn, wp_b, bp, out);
}